// Round 1
// baseline (205.453 us; speedup 1.0000x reference)
//
#include <hip/hip_runtime.h>
#include <math.h>

// ---------------------------------------------------------------------------
// SlidingWindowGQA: x[2,2048,2048] f32, wq[2048,2048], wk/wv[2048,512], wo[2048,2048]
// out f32 [2,2048,2048].  B=2 S=2048 H=16 KVH=4 D=128 WINDOW=512.
// Pipeline: convert->bf16, fused QKV GEMM (MFMA), RoPE, V-transpose,
//           flash sliding-window GQA (swapped QK^T + 16x16x16 PV), out GEMM.
// ---------------------------------------------------------------------------

typedef unsigned short u16;
typedef __attribute__((ext_vector_type(4))) float f32x4;
typedef __attribute__((ext_vector_type(8))) __bf16 bf16x8;
typedef __attribute__((ext_vector_type(4))) __bf16 bf16x4;
typedef __attribute__((ext_vector_type(4))) short s16x4;
typedef __attribute__((ext_vector_type(8))) unsigned short u16x8;
typedef __attribute__((ext_vector_type(4))) unsigned short u16x4;

#define DEV static __device__ __forceinline__

DEV float bf2f(u16 h) {
    union { unsigned int i; float f; } x;
    x.i = ((unsigned int)h) << 16;
    return x.f;
}
DEV u16 f2bf(float f) {
    union { float f; unsigned int i; } x;
    x.f = f;
    unsigned int u = x.i;
    return (u16)((u + 0x7FFFu + ((u >> 16) & 1u)) >> 16);
}

DEV f32x4 mfma32(bf16x8 a, bf16x8 b, f32x4 c) {
    return __builtin_amdgcn_mfma_f32_16x16x32_bf16(a, b, c, 0, 0, 0);
}
DEV f32x4 mfma16(bf16x4 a, bf16x4 b, f32x4 c) {
#if __has_builtin(__builtin_amdgcn_mfma_f32_16x16x16_bf16)
    return __builtin_amdgcn_mfma_f32_16x16x16_bf16(a, b, c, 0, 0, 0);
#else
    union { bf16x4 v; s16x4 s; } ua, ub;
    ua.v = a; ub.v = b;
    return __builtin_amdgcn_mfma_f32_16x16x16bf16_1k(ua.s, ub.s, c, 0, 0, 0);
#endif
}

DEV void gload_lds16(const void* g, void* lds) {
    __builtin_amdgcn_global_load_lds(
        (const __attribute__((address_space(1))) unsigned int*)g,
        (__attribute__((address_space(3))) unsigned int*)lds, 16, 0, 0);
}

// ---------------------------------------------------------------------------
// cos/sin table: ct/st[s][d], s in [0,2048), d in [0,64)
__global__ __launch_bounds__(256) void sincos_kernel(float* ct, float* st) {
    int idx = blockIdx.x * 256 + threadIdx.x;      // 131072 total
    int s = idx >> 6, d = idx & 63;
    // inv_freq = 10000^(-d/64) = 2^(-d*log2(10000)/64)
    float inv = exp2f(-(float)d * (13.287712379549449f / 64.f));
    float a = (float)s * inv;
    float sv, cv;
    sincosf(a, &sv, &cv);
    ct[idx] = cv;
    st[idx] = sv;
}

// f32 -> bf16 straight convert, 4 elems/thread
__global__ __launch_bounds__(256) void f32_to_bf16_kernel(const float* in, u16* out, int n4) {
    int i = blockIdx.x * 256 + threadIdx.x;
    if (i >= n4) return;
    float4 v = ((const float4*)in)[i];
    u16x4 o;
    o[0] = f2bf(v.x); o[1] = f2bf(v.y); o[2] = f2bf(v.z); o[3] = f2bf(v.w);
    ((u16x4*)out)[i] = o;
}

// f32 [R][C] (ld=ldi) -> bf16 [C][R] (ld=ldo), 32x32 LDS tile transpose
__global__ __launch_bounds__(256) void convT_kernel(const float* in, int ldi, u16* out, int ldo) {
    __shared__ float tile[32][33];
    int cc = threadIdx.x & 31, rb = threadIdx.x >> 5;
    long r0 = (long)blockIdx.y * 32, c0 = (long)blockIdx.x * 32;
#pragma unroll
    for (int i = 0; i < 4; i++)
        tile[rb + i * 8][cc] = in[(r0 + rb + i * 8) * (long)ldi + c0 + cc];
    __syncthreads();
#pragma unroll
    for (int i = 0; i < 4; i++)
        out[(c0 + rb + i * 8) * (long)ldo + r0 + cc] = f2bf(tile[cc][rb + i * 8]);
}

// bf16 [R][C] -> bf16 [C][R], batched
__global__ __launch_bounds__(256) void transpose_bf16_kernel(const u16* in, int ldi, long in_bs,
                                                             u16* out, int ldo, long out_bs) {
    __shared__ u16 tile[32][33];
    in += (long)blockIdx.z * in_bs;
    out += (long)blockIdx.z * out_bs;
    int cc = threadIdx.x & 31, rb = threadIdx.x >> 5;
    long r0 = (long)blockIdx.y * 32, c0 = (long)blockIdx.x * 32;
#pragma unroll
    for (int i = 0; i < 4; i++)
        tile[rb + i * 8][cc] = in[(r0 + rb + i * 8) * (long)ldi + c0 + cc];
    __syncthreads();
#pragma unroll
    for (int i = 0; i < 4; i++)
        out[(c0 + rb + i * 8) * (long)ldo + r0 + cc] = tile[cc][rb + i * 8];
}

// RoPE in-place on bf16 [4096][ld], heads of 128, pairs (d, d+64), 8 pairs/thread
__global__ __launch_bounds__(256) void rope_kernel(u16* base, int ld, int nheads,
                                                   const float* ct, const float* st, int total) {
    int idx = blockIdx.x * 256 + threadIdx.x;
    if (idx >= total) return;
    int per_row = nheads * 8;
    int m = idx / per_row;
    int rest = idx - m * per_row;
    int hh = rest >> 3;
    int d0 = (rest & 7) * 8;
    int s = m & 2047;
    u16* p1 = base + (long)m * ld + hh * 128 + d0;
    u16* p2 = p1 + 64;
    u16x8 v1 = *(const u16x8*)p1;
    u16x8 v2 = *(const u16x8*)p2;
    const float* cp = ct + s * 64 + d0;
    const float* sp = st + s * 64 + d0;
    u16x8 o1, o2;
#pragma unroll
    for (int j = 0; j < 8; j++) {
        float x1 = bf2f(v1[j]), x2 = bf2f(v2[j]);
        float cc = cp[j], ss = sp[j];
        o1[j] = f2bf(x1 * cc - x2 * ss);
        o2[j] = f2bf(x2 * cc + x1 * ss);
    }
    *(u16x8*)p1 = o1;
    *(u16x8*)p2 = o2;
}

// ---------------------------------------------------------------------------
// GEMM: C[M][N] = A[M][K](bf16,row) * Bt[N][K](bf16,row)^T.
// 128x128 tile, BK=32, 4 waves (2x2), double-buffered LDS, global_load_lds(16B),
// XOR swizzle chunk^=((row>>1)&3) -> 2-way (free) ds_read_b128 conflicts.
template <bool OUT_BF16>
__global__ __launch_bounds__(256) void gemm_bt_kernel(const u16* A, const u16* Bt, void* Cout,
                                                      int M, int N, int K) {
    __shared__ u16 As[2][128 * 32];
    __shared__ u16 Bs[2][128 * 32];
    const int tid = threadIdx.x;
    const int w = tid >> 6, l = tid & 63, g = l >> 4, c = l & 15;
    const int wm = w >> 1, wn = w & 1;
    const long m0 = (long)blockIdx.y * 128, n0 = (long)blockIdx.x * 128;
    const int nk = K >> 5;

    f32x4 acc[4][4];
    const f32x4 zero = {0.f, 0.f, 0.f, 0.f};
#pragma unroll
    for (int i = 0; i < 4; i++)
#pragma unroll
        for (int j = 0; j < 4; j++) acc[i][j] = zero;

    auto stage = [&](int buf, int kt) {
#pragma unroll
        for (int i = 0; i < 2; i++) {
            int o = (i * 256 + tid) * 16;
            int row = o >> 6;
            int cl = ((o >> 4) & 3) ^ ((row >> 1) & 3);
            gload_lds16(A + (m0 + row) * (long)K + kt * 32 + cl * 8,
                        (void*)&As[buf][(i * 256 + w * 64) * 8]);
        }
#pragma unroll
        for (int i = 0; i < 2; i++) {
            int o = (i * 256 + tid) * 16;
            int row = o >> 6;
            int cl = ((o >> 4) & 3) ^ ((row >> 1) & 3);
            gload_lds16(Bt + (n0 + row) * (long)K + kt * 32 + cl * 8,
                        (void*)&Bs[buf][(i * 256 + w * 64) * 8]);
        }
    };

    stage(0, 0);
    __syncthreads();
    int buf = 0;
    for (int kt = 0; kt < nk; ++kt) {
        if (kt + 1 < nk) stage(buf ^ 1, kt + 1);
        bf16x8 af[4], bf[4];
#pragma unroll
        for (int i = 0; i < 4; i++) {
            int rowa = wm * 64 + i * 16 + c;
            int cha = g ^ ((rowa >> 1) & 3);
            af[i] = *(const bf16x8*)&As[buf][rowa * 32 + cha * 8];
            int rowb = wn * 64 + i * 16 + c;
            int chb = g ^ ((rowb >> 1) & 3);
            bf[i] = *(const bf16x8*)&Bs[buf][rowb * 32 + chb * 8];
        }
#pragma unroll
        for (int i = 0; i < 4; i++)
#pragma unroll
            for (int j = 0; j < 4; j++) acc[i][j] = mfma32(af[i], bf[j], acc[i][j]);
        __syncthreads();
        buf ^= 1;
    }

#pragma unroll
    for (int i = 0; i < 4; i++)
#pragma unroll
        for (int j = 0; j < 4; j++) {
            long row0 = m0 + wm * 64 + i * 16 + g * 4;
            long col = n0 + wn * 64 + j * 16 + c;
#pragma unroll
            for (int r = 0; r < 4; r++) {
                float v = acc[i][j][r];
                if (OUT_BF16)
                    ((u16*)Cout)[(row0 + r) * (long)N + col] = f2bf(v);
                else
                    ((float*)Cout)[(row0 + r) * (long)N + col] = v;
            }
        }
}

// ---------------------------------------------------------------------------
// Flash sliding-window GQA.
// Block: 256 thr = 4 waves; (b, h, q-tile of 64). Wave owns 16 q-rows.
// Swapped QK^T: S^T = mfma32(K_frag, Q^T_frag)  -> lane holds q=lane&15 columns.
// S^T D-layout (row=(g*4)+r) == 16x16x16 A-layout (k=(g*4)+j): P feeds PV directly.
// K LDS [64][128] swz chunk^=(row&15); V^T LDS [128][64] swz chunk^=(row&7).
#define ATT_SCALE 0.08838834764831845f
#define L2E 1.4426950408889634f

__global__ __launch_bounds__(256) void attn_kernel(const u16* QKV, const u16* Vt, u16* AO) {
    __shared__ u16 Ks[64 * 128];
    __shared__ u16 Vs[128 * 64];
    const int tid = threadIdx.x;
    const int w = tid >> 6, l = tid & 63, g = l >> 4, c = l & 15;
    const int Tq = blockIdx.x;
    const int h = blockIdx.y;
    const int b = blockIdx.z;
    const int kvh = h >> 2;
    const int q0 = Tq * 64;
    const int qb = q0 + w * 16;

    bf16x8 bq[4];
    {
        const u16* qrow = QKV + (long)(b * 2048 + qb + c) * 3072 + h * 128;
#pragma unroll
        for (int kc = 0; kc < 4; kc++) bq[kc] = *(const bf16x8*)(qrow + kc * 32 + g * 8);
    }

    f32x4 acc_o[8];
    const f32x4 zero = {0.f, 0.f, 0.f, 0.f};
#pragma unroll
    for (int i = 0; i < 8; i++) acc_o[i] = zero;
    float m_run = -3.0e38f, l_run = 0.f;

    const int t_lo = (q0 > 511) ? ((q0 - 511) >> 6) : 0;
    const int t_hi = Tq;

    for (int t = t_lo; t <= t_hi; ++t) {
        const int kv0 = t * 64;
        // stage K tile [64][128] (swizzled)
#pragma unroll
        for (int i = 0; i < 4; i++) {
            int o = (i * 256 + tid) * 16;
            int key = o >> 8;
            int cl = ((o >> 4) & 15) ^ (key & 15);
            gload_lds16(QKV + (long)(b * 2048 + kv0 + key) * 3072 + 2048 + kvh * 128 + cl * 8,
                        (void*)&Ks[(i * 256 + w * 64) * 8]);
        }
        // stage V^T tile [128][64] (swizzled)
#pragma unroll
        for (int i = 0; i < 4; i++) {
            int o = (i * 256 + tid) * 16;
            int d = o >> 7;
            int cl = ((o >> 4) & 7) ^ (d & 7);
            gload_lds16(Vt + (long)((b * 4 + kvh) * 128 + d) * 2048 + kv0 + cl * 8,
                        (void*)&Vs[(i * 256 + w * 64) * 8]);
        }
        __syncthreads();

        // S^T tiles (n = key group of 16)
        f32x4 sacc[4];
#pragma unroll
        for (int n = 0; n < 4; n++) {
            sacc[n] = zero;
#pragma unroll
            for (int kc = 0; kc < 4; kc++) {
                int row = n * 16 + c;
                int ch = (kc * 4 + g) ^ c;
                bf16x8 kf = *(const bf16x8*)&Ks[row * 128 + ch * 8];
                sacc[n] = mfma32(kf, bq[kc], sacc[n]);
            }
        }

        // online softmax, per query q = qb + c (spread over g via shfl)
        const bool edge = (kv0 + 63 > qb) || (kv0 < qb + 15 - 511);
        float p[4][4];
        float m_tile = -3.0e38f;
#pragma unroll
        for (int n = 0; n < 4; n++)
#pragma unroll
            for (int r = 0; r < 4; r++) {
                float s = sacc[n][r] * ATT_SCALE;
                if (edge) {
                    int j = kv0 + n * 16 + 4 * g + r;
                    int q = qb + c;
                    if (j > q || j < q - 511) s = -__builtin_inff();
                }
                p[n][r] = s;
                m_tile = fmaxf(m_tile, s);
            }
        m_tile = fmaxf(m_tile, __shfl_xor(m_tile, 16));
        m_tile = fmaxf(m_tile, __shfl_xor(m_tile, 32));
        float m_new = fmaxf(m_run, m_tile);   // finite (>= -3e38)
        float alpha = exp2f((m_run - m_new) * L2E);
        float lsum = 0.f;
#pragma unroll
        for (int n = 0; n < 4; n++)
#pragma unroll
            for (int r = 0; r < 4; r++) {
                float e = exp2f((p[n][r] - m_new) * L2E);
                p[n][r] = e;
                lsum += e;
            }
        lsum += __shfl_xor(lsum, 16);
        lsum += __shfl_xor(lsum, 32);
        l_run = l_run * alpha + lsum;
        m_run = m_new;

        // rescale O (rows q = 4g + r) by that row's alpha
        float alpha_r[4];
#pragma unroll
        for (int r = 0; r < 4; r++) alpha_r[r] = __shfl(alpha, (g << 4) + 4 * g + r);
#pragma unroll
        for (int dn = 0; dn < 8; dn++) {
            f32x4 t2 = acc_o[dn];
            t2[0] *= alpha_r[0]; t2[1] *= alpha_r[1];
            t2[2] *= alpha_r[2]; t2[3] *= alpha_r[3];
            acc_o[dn] = t2;
        }

        // P fragments (A-operand of 16x16x16): lane's own regs, no exchange
        bf16x4 ap[4];
#pragma unroll
        for (int n = 0; n < 4; n++) {
            union { u16x4 u; bf16x4 b; } pk;
            pk.u[0] = f2bf(p[n][0]); pk.u[1] = f2bf(p[n][1]);
            pk.u[2] = f2bf(p[n][2]); pk.u[3] = f2bf(p[n][3]);
            ap[n] = pk.b;
        }

        // PV: O[q][d] += P[q][key] * V[key][d]
#pragma unroll
        for (int n = 0; n < 4; n++)
#pragma unroll
            for (int dn = 0; dn < 8; dn++) {
                int row = dn * 16 + c;
                int ch = (2 * n + (g >> 1)) ^ (c & 7);
                bf16x4 vf = *(const bf16x4*)&Vs[row * 64 + ch * 8 + (g & 1) * 4];
                acc_o[dn] = mfma16(ap[n], vf, acc_o[dn]);
            }
        __syncthreads();
    }

    float lr[4];
#pragma unroll
    for (int r = 0; r < 4; r++) {
        float lq = __shfl(l_run, (g << 4) + 4 * g + r);
        lr[r] = 1.f / lq;
    }
#pragma unroll
    for (int dn = 0; dn < 8; dn++)
#pragma unroll
        for (int r = 0; r < 4; r++) {
            long row = (long)(b * 2048 + qb + 4 * g + r);
            AO[row * 2048 + h * 128 + dn * 16 + c] = f2bf(acc_o[dn][r] * lr[r]);
        }
}

// ---------------------------------------------------------------------------
extern "C" void kernel_launch(void* const* d_in, const int* in_sizes, int n_in,
                              void* d_out, int out_size, void* d_ws, size_t ws_size,
                              hipStream_t stream) {
    const float* x = (const float*)d_in[0];
    const float* wq = (const float*)d_in[1];
    const float* wk = (const float*)d_in[2];
    const float* wv = (const float*)d_in[3];
    const float* wo = (const float*)d_in[4];
    float* out = (float*)d_out;

    char* ws = (char*)d_ws;
    u16* xb = (u16*)(ws);                         // [4096][2048]        16.78 MB
    u16* wAll = (u16*)(ws + 16777216);            // [3072][2048] (BT)   12.58 MB
    u16* woT = (u16*)(ws + 29360128);             // [2048][2048] (BT)    8.39 MB
    u16* QKV = (u16*)(ws + 37748736);             // [4096][3072]        25.17 MB
    u16* Vt = (u16*)(ws + 62914560);              // [1024][2048]         4.19 MB
    u16* AO = (u16*)(ws + 67108864);              // [4096][2048]        16.78 MB
    float* ct = (float*)(ws + 83886080);          // [2048][64]
    float* st = (float*)(ws + 84410368);          // [2048][64]

    sincos_kernel<<<512, 256, 0, stream>>>(ct, st);
    f32_to_bf16_kernel<<<8192, 256, 0, stream>>>(x, xb, 2097152);
    convT_kernel<<<dim3(64, 64), 256, 0, stream>>>(wq, 2048, wAll, 2048);
    convT_kernel<<<dim3(16, 64), 256, 0, stream>>>(wk, 512, wAll + (long)2048 * 2048, 2048);
    convT_kernel<<<dim3(16, 64), 256, 0, stream>>>(wv, 512, wAll + (long)2560 * 2048, 2048);
    convT_kernel<<<dim3(64, 64), 256, 0, stream>>>(wo, 2048, woT, 2048);

    gemm_bt_kernel<true><<<dim3(24, 32), 256, 0, stream>>>(xb, wAll, QKV, 4096, 3072, 2048);

    rope_kernel<<<2048, 256, 0, stream>>>(QKV, 3072, 16, ct, st, 524288);
    rope_kernel<<<512, 256, 0, stream>>>(QKV + 2048, 3072, 4, ct, st, 131072);

    transpose_bf16_kernel<<<dim3(16, 64, 2), 256, 0, stream>>>(
        QKV + 2560, 3072, (long)2048 * 3072, Vt, 2048, (long)512 * 2048);

    attn_kernel<<<dim3(32, 16, 2), 256, 0, stream>>>(QKV, Vt, AO);

    gemm_bt_kernel<false><<<dim3(16, 32), 256, 0, stream>>>(AO, woT, out, 4096, 2048, 2048);
}